// Round 5
// baseline (3814.374 us; speedup 1.0000x reference)
//
#include <hip/hip_runtime.h>
#include <math.h>

#define TPB 256

typedef _Float16 f16;
typedef _Float16 half8 __attribute__((ext_vector_type(8)));
typedef _Float16 f16x2 __attribute__((ext_vector_type(2)));
typedef _Float16 f16x4 __attribute__((ext_vector_type(4)));
typedef float floatx4 __attribute__((ext_vector_type(4)));

static constexpr int CDIM = 512;
static constexpr int HWD = 2304;
static constexpr float ALPHA = 0.05f;
static constexpr float TOLF = 4.608e-4f;   // B*HW*1e-7

enum { EPI_F32 = 0, EPI_F16BIASN = 1, EPI_F16BIASM = 2, EPI_F16 = 3,
       EPI_WTW = 4, EPI_MEANSTD = 5, EPI_FISTA = 6 };

__device__ __forceinline__ bool fista_done(const float* __restrict__ diffArr, int iter) {
    bool done = false;
    for (int j = 0; j < iter; ++j) done = done || (diffArr[j] <= TOLF);
    return done;
}

// Generic fp16 MFMA GEMM: C[m,n] = sum_k A[m][k]*B[n][k]  (both operands k-contig).
// Block 128x64, BK=64, 256 threads = 4 waves (2x2); per-wave 64x32 via 4x2 frags of 16x16x32.
// 21.3 FLOP/LDS-byte (vs 16 at 64x64 block) + staging amortized over 2x block area:
// model predicts MfmaUtil 17% -> ~36%. Grids: FISTA 288, WtW 648, logits 1296 blocks.
// LDS XOR-swizzle: 16B chunk s of row R stored at slot s^(R&7) (bank-conflict-free, measured 0).
template<int EPI>
__global__ __launch_bounds__(TPB, 3) void sgemm(
    const f16* __restrict__ A, long a_bs, int lda,
    const f16* __restrict__ B, long b_bs, int ldb,
    void* __restrict__ C0, long c_bs, int ldc,
    void* __restrict__ C1,
    int K,
    const float* __restrict__ bias,
    const float* __restrict__ xAf,
    float* __restrict__ zf, float* __restrict__ yf, f16* __restrict__ yhp,
    const float* __restrict__ lrs, float coef,
    float* __restrict__ diffArr, int iter)
{
    if (EPI == EPI_FISTA) {
        if (iter > 0 && fista_done(diffArr, iter)) return;
    }
    __shared__ f16 As[128 * 64];
    __shared__ f16 Bs[64 * 64];
    const int tid = threadIdx.x;
    const int wid = tid >> 6, lane = tid & 63;
    const int wr = wid >> 1, wc = wid & 1;      // wave covers rows [wr*64,+64), cols [wc*32,+32)
    const int m0 = blockIdx.y << 7, n0 = blockIdx.x << 6;
    const f16* Ab = A + (long)blockIdx.z * a_bs;
    const f16* Bb = B + (long)blockIdx.z * b_bs;

    floatx4 acc[4][2] = {};
    floatx4 acc2[4][2] = {};   // only used by MEANSTD (DCE'd otherwise)

    const int rl = lane & 15, kg = lane >> 4;

    for (int k0 = 0; k0 < K; k0 += 64) {
        #pragma unroll
        for (int p = 0; p < 4; ++p) {           // A: 128 rows x 8 chunks = 1024
            const int c = p * 256 + tid;
            const int R = c >> 3, s = c & 7;
            *(int4*)&As[R * 64 + (s ^ (R & 7)) * 8] =
                *(const int4*)(Ab + (long)(m0 + R) * lda + k0 + s * 8);
        }
        #pragma unroll
        for (int p = 0; p < 2; ++p) {           // B: 64 rows x 8 chunks = 512
            const int c = p * 256 + tid;
            const int R = c >> 3, s = c & 7;
            *(int4*)&Bs[R * 64 + (s ^ (R & 7)) * 8] =
                *(const int4*)(Bb + (long)(n0 + R) * ldb + k0 + s * 8);
        }
        __syncthreads();
        #pragma unroll
        for (int kk = 0; kk < 2; ++kk) {
            const int j = kk * 4 + kg;
            half8 af[4], bf[2];
            #pragma unroll
            for (int f = 0; f < 4; ++f) {
                const int ra = wr * 64 + f * 16 + rl;
                af[f] = *(const half8*)&As[ra * 64 + ((j ^ (ra & 7)) * 8)];
            }
            #pragma unroll
            for (int f = 0; f < 2; ++f) {
                const int rb = wc * 32 + f * 16 + rl;
                bf[f] = *(const half8*)&Bs[rb * 64 + ((j ^ (rb & 7)) * 8)];
            }
            #pragma unroll
            for (int fi = 0; fi < 4; ++fi) {
                #pragma unroll
                for (int fj = 0; fj < 2; ++fj) {
                    acc[fi][fj] = __builtin_amdgcn_mfma_f32_16x16x32_f16(af[fi], bf[fj], acc[fi][fj], 0, 0, 0);
                    if constexpr (EPI == EPI_MEANSTD) {
                        half8 bq = bf[fj] * bf[fj];
                        acc2[fi][fj] = __builtin_amdgcn_mfma_f32_16x16x32_f16(af[fi], bq, acc2[fi][fj], 0, 0, 0);
                    }
                }
            }
        }
        __syncthreads();
    }

    const int rg = lane >> 4;
    const int bz = blockIdx.z;
    float loc = 0.f;
    float lr = 0.f, sh = 0.f;
    if constexpr (EPI == EPI_FISTA) { lr = lrs[0]; sh = lrs[1]; }

    #pragma unroll
    for (int fi = 0; fi < 4; ++fi) {
        #pragma unroll
        for (int fj = 0; fj < 2; ++fj) {
            #pragma unroll
            for (int r = 0; r < 4; ++r) {
                const int row = m0 + wr * 64 + fi * 16 + rg * 4 + r;
                const int col = n0 + wc * 32 + fj * 16 + rl;
                const float v = acc[fi][fj][r];
                if constexpr (EPI == EPI_F32) {
                    ((float*)C0)[bz * c_bs + (long)row * ldc + col] = v;
                } else if constexpr (EPI == EPI_F16BIASN) {
                    ((f16*)C0)[bz * c_bs + (long)row * ldc + col] = (f16)(v + bias[col]);
                } else if constexpr (EPI == EPI_F16BIASM) {
                    ((f16*)C0)[bz * c_bs + (long)row * ldc + col] = (f16)(v + bias[row]);
                } else if constexpr (EPI == EPI_F16) {
                    ((f16*)C0)[bz * c_bs + (long)row * ldc + col] = (f16)v;
                } else if constexpr (EPI == EPI_WTW) {
                    ((float*)C0)[(long)row * ldc + col] = v;
                    ((f16*)C1)[(long)row * ldc + col] = (f16)v;
                } else if constexpr (EPI == EPI_MEANSTD) {
                    const float m_ = v;
                    float s2 = acc2[fi][fj][r] - m_ * m_;
                    const long o = ((long)bz * CDIM + col) * HWD + row;
                    ((f16*)C0)[o] = (f16)m_;
                    ((f16*)C1)[o] = (f16)sqrtf(s2 > 0.f ? s2 : 0.f);
                } else {  // EPI_FISTA: grad = acc - xA; f32 proximal state; f16 GEMM operand
                    const long off = (long)row * HWD + col;
                    const float grad = v - xAf[off];
                    const float zo = zf[off];
                    const float p = yf[off] - lr * grad;
                    const float ap = fabsf(p) - sh;
                    const float zn = ap > 0.f ? copysignf(ap, p) : 0.f;
                    zf[off] = zn;
                    const float yn = zn + coef * (zn - zo);
                    yf[off] = yn;
                    yhp[off] = (f16)yn;
                    loc += fabsf(zn - zo);
                }
            }
        }
    }
    if constexpr (EPI == EPI_FISTA) {
        __shared__ float red[TPB];
        red[tid] = loc; __syncthreads();
        for (int s = 128; s > 0; s >>= 1) { if (tid < s) red[tid] += red[tid + s]; __syncthreads(); }
        if (tid == 0) atomicAdd(&diffArr[iter], red[0]);
    }
}

// f32 [b][R][Cc] -> f16 [b][Cc][R]
__global__ __launch_bounds__(TPB) void tcvt(const float* __restrict__ in, long in_bs,
                                            f16* __restrict__ out, long out_bs, int R, int Cc) {
    __shared__ float t[32][33];
    const int b = blockIdx.z;
    const int r0 = blockIdx.y << 5, c0 = blockIdx.x << 5;
    const int tx = threadIdx.x & 31, ty = threadIdx.x >> 5;
    const float* ib = in + (long)b * in_bs;
    #pragma unroll
    for (int p = 0; p < 4; ++p) {
        const int r = ty + p * 8;
        t[r][tx] = ib[(long)(r0 + r) * Cc + c0 + tx];
    }
    __syncthreads();
    f16* ob = out + (long)b * out_bs;
    #pragma unroll
    for (int p = 0; p < 4; ++p) {
        const int c = ty + p * 8;
        ob[(long)(c0 + c) * R + r0 + tx] = (f16)t[tx][c];
    }
}

__global__ void cvt16(const float4* __restrict__ in, f16x4* __restrict__ out, long n4) {
    long i = (long)blockIdx.x * blockDim.x + threadIdx.x;
    const long st = (long)gridDim.x * blockDim.x;
    for (; i < n4; i += st) {
        const float4 v = in[i];
        f16x4 o; o.x = (f16)v.x; o.y = (f16)v.y; o.z = (f16)v.z; o.w = (f16)v.w;
        out[i] = o;
    }
}

// row softmax with the row staged in LDS (one global read + one f16 write)
__global__ __launch_bounds__(TPB) void softmax_h(const float* __restrict__ Sf, f16* __restrict__ Sh) {
    __shared__ float row[HWD];
    __shared__ float red[TPB];
    const long base = (long)blockIdx.x * HWD;
    const int tid = threadIdx.x;
    float mx = -3.4e38f;
    for (int i = tid; i < HWD; i += TPB) { const float v = Sf[base + i]; row[i] = v; mx = fmaxf(mx, v); }
    red[tid] = mx; __syncthreads();
    for (int s = 128; s > 0; s >>= 1) { if (tid < s) red[tid] = fmaxf(red[tid], red[tid + s]); __syncthreads(); }
    mx = red[0]; __syncthreads();
    float sum = 0.f;
    for (int i = tid; i < HWD; i += TPB) { const float e = expf(row[i] - mx); row[i] = e; sum += e; }
    red[tid] = sum; __syncthreads();
    for (int s = 128; s > 0; s >>= 1) { if (tid < s) red[tid] += red[tid + s]; __syncthreads(); }
    const float inv = 1.0f / red[0];
    for (int i = tid; i < HWD; i += TPB) Sh[base + i] = (f16)(row[i] * inv);
}

// group-norm (256 groups of 9) + scale/shift -> x (fp16)
__global__ __launch_bounds__(TPB) void groupnorm_x(const float* __restrict__ contc,
                                                   const float* __restrict__ meanc,
                                                   const float* __restrict__ stdc,
                                                   f16* __restrict__ xh) {
    const long base = (long)blockIdx.x * HWD + (long)threadIdx.x * 9;
    float v[9];
    float mu = 0.f;
    #pragma unroll
    for (int j = 0; j < 9; ++j) { v[j] = contc[base + j]; mu += v[j]; }
    mu *= (1.0f / 9.0f);
    float var = 0.f;
    #pragma unroll
    for (int j = 0; j < 9; ++j) { const float d = v[j] - mu; var += d * d; }
    var *= (1.0f / 8.0f);
    const float rs = 1.0f / sqrtf(var + 1e-5f);
    #pragma unroll
    for (int j = 0; j < 9; ++j)
        xh[base + j] = (f16)((v[j] - mu) * rs * (float)stdc[base + j] + (float)meanc[base + j]);
}

// power-iteration matvec on fp16 matrix, with input normalization folded in
__global__ __launch_bounds__(TPB) void matvec_h(const f16* __restrict__ Wm,
                                                const float* __restrict__ win,
                                                float* __restrict__ wout) {
    __shared__ float red[TPB];
    const int tid = threadIdx.x;
    float s = 0.f;
    for (int i = tid; i < HWD; i += TPB) { const float v = win[i]; s += v * v; }
    red[tid] = s; __syncthreads();
    for (int st = 128; st > 0; st >>= 1) { if (tid < st) red[tid] += red[tid + st]; __syncthreads(); }
    const float ninv = rsqrtf(red[0]);
    const int row = (blockIdx.x << 2) + (tid >> 6);
    const int lane = tid & 63;
    const f16x2* wr2 = (const f16x2*)(Wm + (long)row * HWD);
    float d = 0.f;
    for (int j = lane; j < HWD / 2; j += 64) {
        const f16x2 p = wr2[j];
        d += (float)p.x * win[2 * j] + (float)p.y * win[2 * j + 1];
    }
    #pragma unroll
    for (int o = 32; o > 0; o >>= 1) d += __shfl_down(d, o);
    if (lane == 0) wout[row] = d * ninv;
}

// L = (w . Wf w) / (w . w)
__global__ __launch_bounds__(TPB) void kernelL(const float* __restrict__ Wf,
                                               const float* __restrict__ w,
                                               float* __restrict__ Lnum, float* __restrict__ Lden) {
    __shared__ float red[TPB];
    const int tid = threadIdx.x;
    const int row = (blockIdx.x << 2) + (tid >> 6);
    const int lane = tid & 63;
    const float* wr = Wf + (long)row * HWD;
    float d = 0.f;
    for (int j = lane; j < HWD; j += 64) d += wr[j] * w[j];
    #pragma unroll
    for (int o = 32; o > 0; o >>= 1) d += __shfl_down(d, o);
    red[tid] = (lane == 0) ? d * w[row] : 0.f;
    __syncthreads();
    for (int s = 128; s > 0; s >>= 1) { if (tid < s) red[tid] += red[tid + s]; __syncthreads(); }
    if (tid == 0) atomicAdd(Lnum, red[0]);
    if (blockIdx.x == 0) {
        __syncthreads();
        float s2 = 0.f;
        for (int i = tid; i < HWD; i += TPB) { const float v = w[i]; s2 += v * v; }
        red[tid] = s2; __syncthreads();
        for (int s = 128; s > 0; s >>= 1) { if (tid < s) red[tid] += red[tid + s]; __syncthreads(); }
        if (tid == 0) *Lden = red[0];
    }
}

__global__ void lr_fin(const float* __restrict__ Lnum, const float* __restrict__ Lden,
                       float* __restrict__ lrs) {
    const float lr = Lden[0] / Lnum[0];
    lrs[0] = lr;
    lrs[1] = ALPHA * lr;
}

__global__ void init_small(float* __restrict__ wvec, float* __restrict__ diffArr,
                           float* __restrict__ Lnum) {
    const int tid = threadIdx.x;
    for (int i = tid; i < HWD; i += TPB) wvec[i] = (float)(1.0 / 48.0);
    if (tid < 43) diffArr[tid] = 0.f;
    if (tid == 64) Lnum[0] = 0.f;
}

__global__ void zero_kernel(float4* __restrict__ p, long n4) {
    long i = (long)blockIdx.x * blockDim.x + threadIdx.x;
    const long st = (long)gridDim.x * blockDim.x;
    for (; i < n4; i += st) p[i] = make_float4(0.f, 0.f, 0.f, 0.f);
}

__global__ void copy_kernel(const float4* __restrict__ s, float4* __restrict__ d, long n4) {
    long i = (long)blockIdx.x * blockDim.x + threadIdx.x;
    const long st = (long)gridDim.x * blockDim.x;
    for (; i < n4; i += st) d[i] = s[i];
}

extern "C" void kernel_launch(void* const* d_in, const int* in_sizes, int n_in,
                              void* d_out, int out_size, void* d_ws, size_t ws_size,
                              hipStream_t stream) {
    (void)in_sizes; (void)n_in; (void)out_size;
    const float* content = (const float*)d_in[0];
    const float* style   = (const float*)d_in[1];
    const float* ckey    = (const float*)d_in[2];
    const float* skey    = (const float*)d_in[3];
    const float* f_w = (const float*)d_in[4];
    const float* f_b = (const float*)d_in[5];
    const float* g_w = (const float*)d_in[6];
    const float* g_b = (const float*)d_in[7];
    const float* h_w = (const float*)d_in[8];
    const float* h_b = (const float*)d_in[9];
    const float* Amat = (const float*)d_in[10];

    if (ws_size < 79500000) return;
    char* W = (char*)d_ws;

    const long E16 = (long)HWD * CDIM;          // 1,179,648
    const long EHH = (long)HWD * HWD;           // 5,308,416
    // ---- arena (byte offsets), phase-overlapped (R1-proven layout, f32 FISTA state) ----
    f16*  ckeyT = (f16*)(W + 0);
    f16*  skeyT = (f16*)(W + 4718592);
    f16*  styleT= (f16*)(W + 9437184);
    float* Sf   = (float*)(W + 0);
    f16*  Ah    = (f16*)(W + 0);
    f16*  At    = (f16*)(W + 10616832);
    f16*  Wh    = (f16*)(W + 21233664);
    f16*  W4h   = (f16*)(W + 31850496);
    f16*  W2h   = (f16*)(W + 0);
    float* contc= (float*)(W + 21233664);       // dead before Wh written
    float* zf   = (float*)(W + 0);
    float* yf   = (float*)(W + 9437184);
    f16*  yh    = (f16*)(W + 31850496);         // overwrites W4h after power iters done
    f16*  Sh    = (f16*)(W + 42467328);
    float* meanc= (float*)(W + 42467328);
    float* stdc = (float*)(W + 42467328 + 9437184);
    float* Wf   = (float*)(W + 42467328);
    float* xAf  = (float*)(W + 42467328);       // overwrites Wf after kernelL
    f16*  Fh    = (f16*)(W + 63700992);
    f16*  Gh    = (f16*)(W + 63700992 + 4718592);
    f16*  Hh    = (f16*)(W + 63700992 + 9437184);
    f16*  meanx = (f16*)(W + 63700992);
    f16*  stdx  = (f16*)(W + 63700992 + 4718592);
    f16*  conth = (f16*)(W + 63700992 + 9437184);
    f16*  xh    = (f16*)(W + 63700992);
    float* w_a  = (float*)(W + 77856768);
    float* w_b  = (float*)(W + 77856768 + 9216);
    float* lrs  = (float*)(W + 77856768 + 18432);
    float* Lnum = (float*)(W + 77856768 + 18440);
    float* Lden = (float*)(W + 77856768 + 18444);
    float* diffArr = (float*)(W + 77856768 + 18448);
    f16*  fwh   = (f16*)(W + 77875712);
    f16*  gwh   = (f16*)(W + 77875712 + 524288);
    f16*  hwh   = (f16*)(W + 77875712 + 1048576);

    init_small<<<1, TPB, 0, stream>>>(w_a, diffArr, Lnum);

    // weight + key conversions
    cvt16<<<256, TPB, 0, stream>>>((const float4*)f_w, (f16x4*)fwh, (long)CDIM * CDIM / 4);
    cvt16<<<256, TPB, 0, stream>>>((const float4*)g_w, (f16x4*)gwh, (long)CDIM * CDIM / 4);
    cvt16<<<256, TPB, 0, stream>>>((const float4*)h_w, (f16x4*)hwh, (long)CDIM * CDIM / 4);
    tcvt<<<dim3(72, 16, 2), TPB, 0, stream>>>(ckey, E16, ckeyT, E16, CDIM, HWD);
    tcvt<<<dim3(72, 16, 2), TPB, 0, stream>>>(skey, E16, skeyT, E16, CDIM, HWD);
    tcvt<<<dim3(72, 16, 2), TPB, 0, stream>>>(style, E16, styleT, E16, CDIM, HWD);

    // convs: Fh[s][c], Gh[s][c] (bias over n=c); Hh[c][s] (bias over m=c)
    sgemm<EPI_F16BIASN><<<dim3(8, 18, 2), TPB, 0, stream>>>(ckeyT, E16, CDIM, fwh, 0, CDIM,
        Fh, E16, CDIM, nullptr, CDIM, f_b, nullptr, nullptr, nullptr, nullptr, nullptr, 0.f, nullptr, 0);
    sgemm<EPI_F16BIASN><<<dim3(8, 18, 2), TPB, 0, stream>>>(skeyT, E16, CDIM, gwh, 0, CDIM,
        Gh, E16, CDIM, nullptr, CDIM, g_b, nullptr, nullptr, nullptr, nullptr, nullptr, 0.f, nullptr, 0);
    sgemm<EPI_F16BIASM><<<dim3(36, 4, 2), TPB, 0, stream>>>(hwh, 0, CDIM, styleT, E16, CDIM,
        Hh, E16, HWD, nullptr, CDIM, h_b, nullptr, nullptr, nullptr, nullptr, nullptr, 0.f, nullptr, 0);

    // logits = Fh . Gh^T -> Sf f32 ; softmax -> Sh f16
    sgemm<EPI_F32><<<dim3(36, 18, 2), TPB, 0, stream>>>(Fh, E16, CDIM, Gh, E16, CDIM,
        Sf, EHH, HWD, nullptr, CDIM, nullptr, nullptr, nullptr, nullptr, nullptr, nullptr, 0.f, nullptr, 0);
    softmax_h<<<2 * HWD, TPB, 0, stream>>>(Sf, Sh);

    // A conversions (into dead Sf space)
    cvt16<<<2048, TPB, 0, stream>>>((const float4*)Amat, (f16x4*)Ah, EHH / 4);
    tcvt<<<dim3(72, 72, 1), TPB, 0, stream>>>(Amat, 0, At, 0, HWD, HWD);

    // mean/std (dual MFMA), transposed write -> meanx/stdx [b*c][q]
    sgemm<EPI_MEANSTD><<<dim3(8, 18, 2), TPB, 0, stream>>>(Sh, EHH, HWD, Hh, E16, HWD,
        meanx, 0, HWD, stdx, HWD, nullptr, nullptr, nullptr, nullptr, nullptr, nullptr, 0.f, nullptr, 0);

    cvt16<<<2048, TPB, 0, stream>>>((const float4*)content, (f16x4*)conth, (long)2 * E16 / 4);

    // projections -> f32 [1024][2304]
    sgemm<EPI_F32><<<dim3(36, 8, 1), TPB, 0, stream>>>(meanx, 0, HWD, Ah, 0, HWD,
        meanc, 0, HWD, nullptr, HWD, nullptr, nullptr, nullptr, nullptr, nullptr, nullptr, 0.f, nullptr, 0);
    sgemm<EPI_F32><<<dim3(36, 8, 1), TPB, 0, stream>>>(stdx, 0, HWD, Ah, 0, HWD,
        stdc, 0, HWD, nullptr, HWD, nullptr, nullptr, nullptr, nullptr, nullptr, nullptr, 0.f, nullptr, 0);
    sgemm<EPI_F32><<<dim3(36, 8, 1), TPB, 0, stream>>>(conth, 0, HWD, Ah, 0, HWD,
        contc, 0, HWD, nullptr, HWD, nullptr, nullptr, nullptr, nullptr, nullptr, nullptr, 0.f, nullptr, 0);

    groupnorm_x<<<1024, TPB, 0, stream>>>(contc, meanc, stdc, xh);

    // WtW (f32 + f16), then W2 = Wh^2, W4 = W2^2 (fp16)
    sgemm<EPI_WTW><<<dim3(36, 18, 1), TPB, 0, stream>>>(At, 0, HWD, At, 0, HWD,
        Wf, 0, HWD, Wh, HWD, nullptr, nullptr, nullptr, nullptr, nullptr, nullptr, 0.f, nullptr, 0);
    sgemm<EPI_F16><<<dim3(36, 18, 1), TPB, 0, stream>>>(Wh, 0, HWD, Wh, 0, HWD,
        W2h, 0, HWD, nullptr, HWD, nullptr, nullptr, nullptr, nullptr, nullptr, nullptr, 0.f, nullptr, 0);
    sgemm<EPI_F16><<<dim3(36, 18, 1), TPB, 0, stream>>>(W2h, 0, HWD, W2h, 0, HWD,
        W4h, 0, HWD, nullptr, HWD, nullptr, nullptr, nullptr, nullptr, nullptr, nullptr, 0.f, nullptr, 0);

    // 25 power iterations on W4 == 100 on W (identical Krylov direction); ends in w_b
    for (int it = 0; it < 25; ++it) {
        const float* win = (it & 1) ? w_b : w_a;
        float* wout = (it & 1) ? w_a : w_b;
        matvec_h<<<HWD / 4, TPB, 0, stream>>>(W4h, win, wout);
    }
    kernelL<<<HWD / 4, TPB, 0, stream>>>(Wf, w_b, Lnum, Lden);
    lr_fin<<<1, 1, 0, stream>>>(Lnum, Lden, lrs);

    // xA (loop-invariant) in f32: xAf = xh . At^T  (overwrites dead Wf)
    sgemm<EPI_F32><<<dim3(36, 8, 1), TPB, 0, stream>>>(xh, 0, HWD, At, 0, HWD,
        xAf, 0, HWD, nullptr, HWD, nullptr, nullptr, nullptr, nullptr, nullptr, nullptr, 0.f, nullptr, 0);

    // z = y = 0 (f32, contiguous: 2 * 2*E16 floats = E16 float4), yh = 0 (f16: E16/4 float4)
    zero_kernel<<<1024, TPB, 0, stream>>>((float4*)zf, E16);
    zero_kernel<<<1024, TPB, 0, stream>>>((float4*)yh, E16 / 4);

    // FISTA: grad = y@WtW - xA, one fused MFMA GEMM per iteration
    float t = 1.0f;
    for (int it = 0; it < 43; ++it) {
        const float tn = (1.0f + sqrtf(1.0f + 4.0f * t * t)) * 0.5f;
        const float coef = (t - 1.0f) / tn;
        t = tn;
        sgemm<EPI_FISTA><<<dim3(36, 8, 1), TPB, 0, stream>>>(yh, 0, HWD, Wh, 0, HWD,
            nullptr, 0, HWD, nullptr, HWD, nullptr, xAf, zf, yf, yh, lrs, coef, diffArr, it);
    }

    // out = z (f32: 2*E16 floats = 2*E16/4 float4)
    copy_kernel<<<2048, TPB, 0, stream>>>((const float4*)zf, (float4*)d_out, 2 * E16 / 4);
}